// Round 1
// baseline (11613.421 us; speedup 1.0000x reference)
//
#include <hip/hip_runtime.h>
#include <math.h>

#define DEPTHL 4
#define HEADS 8
#define DH 64
#define DIM 512
#define BATCH 4
#define SEQ 512
#define ROWS (BATCH*SEQ)
#define SCALE 0.125f
#define LNEPS 1e-5f

// ---------------- block reduction helpers ----------------
__device__ __forceinline__ void blk_sum4(float& a, float& b, float& c, float& d) {
    __shared__ float s[16];
    #pragma unroll
    for (int o = 32; o; o >>= 1) {
        a += __shfl_xor(a, o); b += __shfl_xor(b, o);
        c += __shfl_xor(c, o); d += __shfl_xor(d, o);
    }
    int w = threadIdx.x >> 6;
    if ((threadIdx.x & 63) == 0) { s[w*4+0]=a; s[w*4+1]=b; s[w*4+2]=c; s[w*4+3]=d; }
    __syncthreads();
    a = s[0]+s[4]+s[8]+s[12];
    b = s[1]+s[5]+s[9]+s[13];
    c = s[2]+s[6]+s[10]+s[14];
    d = s[3]+s[7]+s[11]+s[15];
    __syncthreads();
}

__device__ __forceinline__ float blk_max(float v) {
    __shared__ float s[4];
    #pragma unroll
    for (int o = 32; o; o >>= 1) v = fmaxf(v, __shfl_xor(v, o));
    if ((threadIdx.x & 63) == 0) s[threadIdx.x >> 6] = v;
    __syncthreads();
    v = fmaxf(fmaxf(s[0], s[1]), fmaxf(s[2], s[3]));
    __syncthreads();
    return v;
}

__device__ __forceinline__ float blk_sum(float v) {
    __shared__ float s[4];
    #pragma unroll
    for (int o = 32; o; o >>= 1) v += __shfl_xor(v, o);
    if ((threadIdx.x & 63) == 0) s[threadIdx.x >> 6] = v;
    __syncthreads();
    v = s[0]+s[1]+s[2]+s[3];
    __syncthreads();
    return v;
}

// ---------------- complex LayerNorm (separate real/imag LN) ----------------
__global__ __launch_bounds__(256) void ln_kernel(
    const float* __restrict__ xr, const float* __restrict__ xi,
    const float* __restrict__ gr, const float* __restrict__ br,
    const float* __restrict__ gi, const float* __restrict__ bi,
    float* __restrict__ outr, float* __restrict__ outi)
{
    int row = blockIdx.x, t = threadIdx.x;
    float2 vr = ((const float2*)(xr + (size_t)row*DIM))[t];
    float2 vi = ((const float2*)(xi + (size_t)row*DIM))[t];
    float sr = vr.x+vr.y, qr = vr.x*vr.x+vr.y*vr.y;
    float si = vi.x+vi.y, qi = vi.x*vi.x+vi.y*vi.y;
    blk_sum4(sr, qr, si, qi);
    float mr = sr*(1.f/DIM), mi_ = si*(1.f/DIM);
    float rr = 1.f/sqrtf(qr*(1.f/DIM)-mr*mr+LNEPS);
    float ri = 1.f/sqrtf(qi*(1.f/DIM)-mi_*mi_+LNEPS);
    float2 g2r = ((const float2*)gr)[t], b2r = ((const float2*)br)[t];
    float2 g2i = ((const float2*)gi)[t], b2i = ((const float2*)bi)[t];
    float2 o_r, o_i;
    o_r.x = (vr.x-mr)*rr*g2r.x + b2r.x;
    o_r.y = (vr.y-mr)*rr*g2r.y + b2r.y;
    o_i.x = (vi.x-mi_)*ri*g2i.x + b2i.x;
    o_i.y = (vi.y-mi_)*ri*g2i.y + b2i.y;
    ((float2*)(outr + (size_t)row*DIM))[t] = o_r;
    ((float2*)(outi + (size_t)row*DIM))[t] = o_i;
}

// ---------------- complex GEMM: out[r,e] = sum_k A[r,k] * W[e,k] ----------------
// MODE 0: write to per-head layout [b,h,n,d] (QKV)
// MODE 1: += bias[e] + residual[r,e], plain layout (Wout)
// MODE 2: ISTA epilogue: out = crelu(xn + ss*acc - ss*lm) (FF), xn == A
#define BM 64
#define BN 64
#define BK 16

template<int MODE>
__global__ __launch_bounds__(256) void cgemm(
    const float* __restrict__ Ar, const float* __restrict__ Ai,
    const float* __restrict__ Wr, const float* __restrict__ Wi,
    float* __restrict__ Or, float* __restrict__ Oi,
    const float* __restrict__ biasR, const float* __restrict__ biasI,
    const float* __restrict__ resR, const float* __restrict__ resI,
    const float* __restrict__ stepp, const float* __restrict__ lamb, int layer)
{
    __shared__ float sAr[BK][BM+4], sAi[BK][BM+4], sBr[BK][BN+4], sBi[BK][BN+4];
    int tid = threadIdx.x;
    int bm = blockIdx.x, bn = blockIdx.y;
    int tx = tid & 15, ty = tid >> 4;
    int lrow = tid >> 2, lk = (tid & 3) * 4;
    const float* pAr = Ar + (size_t)(bm*BM + lrow)*DIM + lk;
    const float* pAi = Ai + (size_t)(bm*BM + lrow)*DIM + lk;
    const float* pWr = Wr + (size_t)(bn*BN + lrow)*DIM + lk;
    const float* pWi = Wi + (size_t)(bn*BN + lrow)*DIM + lk;
    float cr[4][4] = {{0.f}}, ci[4][4] = {{0.f}};
    for (int k0 = 0; k0 < DIM; k0 += BK) {
        float a_r[4], a_i[4], w_r[4], w_i[4];
        *(float4*)a_r = *(const float4*)(pAr + k0);
        *(float4*)a_i = *(const float4*)(pAi + k0);
        *(float4*)w_r = *(const float4*)(pWr + k0);
        *(float4*)w_i = *(const float4*)(pWi + k0);
        __syncthreads();
        #pragma unroll
        for (int j = 0; j < 4; ++j) {
            sAr[lk+j][lrow] = a_r[j];
            sAi[lk+j][lrow] = a_i[j];
            sBr[lk+j][lrow] = w_r[j];
            sBi[lk+j][lrow] = w_i[j];
        }
        __syncthreads();
        #pragma unroll
        for (int kk = 0; kk < BK; ++kk) {
            float ar[4], ai[4], br[4], bi[4];
            *(float4*)ar = *(const float4*)&sAr[kk][ty*4];
            *(float4*)ai = *(const float4*)&sAi[kk][ty*4];
            *(float4*)br = *(const float4*)&sBr[kk][tx*4];
            *(float4*)bi = *(const float4*)&sBi[kk][tx*4];
            #pragma unroll
            for (int m = 0; m < 4; ++m)
                #pragma unroll
                for (int n = 0; n < 4; ++n) {
                    cr[m][n] = fmaf(ar[m], br[n], cr[m][n]);
                    cr[m][n] = fmaf(-ai[m], bi[n], cr[m][n]);
                    ci[m][n] = fmaf(ar[m], bi[n], ci[m][n]);
                    ci[m][n] = fmaf(ai[m], br[n], ci[m][n]);
                }
        }
    }
    if (MODE == 0) {
        #pragma unroll
        for (int m = 0; m < 4; ++m) {
            int r = bm*BM + ty*4 + m;
            int b = r >> 9, n = r & (SEQ-1);
            size_t off = ((size_t)(b*HEADS + bn)*SEQ + n)*DH + tx*4;
            *(float4*)(Or + off) = make_float4(cr[m][0], cr[m][1], cr[m][2], cr[m][3]);
            *(float4*)(Oi + off) = make_float4(ci[m][0], ci[m][1], ci[m][2], ci[m][3]);
        }
    } else if (MODE == 1) {
        int e = bn*BN + tx*4;
        float4 bR = *(const float4*)(biasR + e);
        float4 bI = *(const float4*)(biasI + e);
        #pragma unroll
        for (int m = 0; m < 4; ++m) {
            int r = bm*BM + ty*4 + m;
            size_t off = (size_t)r*DIM + e;
            float4 xR = *(const float4*)(resR + off);
            float4 xI = *(const float4*)(resI + off);
            float4 oR, oI;
            oR.x = cr[m][0] + bR.x + xR.x; oR.y = cr[m][1] + bR.y + xR.y;
            oR.z = cr[m][2] + bR.z + xR.z; oR.w = cr[m][3] + bR.w + xR.w;
            oI.x = ci[m][0] + bI.x + xI.x; oI.y = ci[m][1] + bI.y + xI.y;
            oI.z = ci[m][2] + bI.z + xI.z; oI.w = ci[m][3] + bI.w + xI.w;
            *(float4*)(Or + off) = oR;
            *(float4*)(Oi + off) = oI;
        }
    } else {
        float ss = log1pf(expf(stepp[layer]));
        float sl = ss * log1pf(expf(lamb[layer]));
        int e = bn*BN + tx*4;
        #pragma unroll
        for (int m = 0; m < 4; ++m) {
            int r = bm*BM + ty*4 + m;
            size_t off = (size_t)r*DIM + e;
            float4 xR = *(const float4*)(Ar + off);   // xn (A itself)
            float4 xI = *(const float4*)(Ai + off);
            float4 oR, oI;
            oR.x = fmaxf(xR.x + ss*cr[m][0] - sl, 0.f);
            oR.y = fmaxf(xR.y + ss*cr[m][1] - sl, 0.f);
            oR.z = fmaxf(xR.z + ss*cr[m][2] - sl, 0.f);
            oR.w = fmaxf(xR.w + ss*cr[m][3] - sl, 0.f);
            oI.x = fmaxf(xI.x + ss*ci[m][0], 0.f);
            oI.y = fmaxf(xI.y + ss*ci[m][1], 0.f);
            oI.z = fmaxf(xI.z + ss*ci[m][2], 0.f);
            oI.w = fmaxf(xI.w + ss*ci[m][3], 0.f);
            *(float4*)(Or + off) = oR;
            *(float4*)(Oi + off) = oI;
        }
    }
}

// ---------------- complex attention, softmax on |z| with phase preserved ----------------
#define RT 8
__global__ __launch_bounds__(256) void attn_kernel(
    const float* __restrict__ whr, const float* __restrict__ whi,  // [B*H, N, DH]
    float* __restrict__ aor, float* __restrict__ aoi)              // [B*N, DIM]
{
    __shared__ float sQr[RT][DH], sQi[RT][DH];
    __shared__ float sZr[RT][SEQ], sZi[RT][SEQ];
    int tid = threadIdx.x;
    int bh = blockIdx.x, rt = blockIdx.y;
    const float* kr = whr + (size_t)bh*SEQ*DH;
    const float* ki = whi + (size_t)bh*SEQ*DH;
    int n0 = rt*RT;
    ((float2*)&sQr[0][0])[tid] = ((const float2*)(kr + (size_t)n0*DH))[tid];
    ((float2*)&sQi[0][0])[tid] = ((const float2*)(ki + (size_t)n0*DH))[tid];
    __syncthreads();
    // phase 1: dots[r,m] = SCALE * sum_d q[r,d] * conj(k[m,d])
    #pragma unroll
    for (int mi = 0; mi < 2; ++mi) {
        int m = mi*256 + tid;
        const float* krow_r = kr + (size_t)m*DH;
        const float* krow_i = ki + (size_t)m*DH;
        float zr[RT], zi[RT];
        #pragma unroll
        for (int r = 0; r < RT; ++r) { zr[r]=0.f; zi[r]=0.f; }
        #pragma unroll
        for (int d0 = 0; d0 < DH; d0 += 16) {
            float k_r[16], k_i[16];
            #pragma unroll
            for (int j = 0; j < 4; ++j) {
                *(float4*)&k_r[4*j] = *(const float4*)(krow_r + d0 + 4*j);
                *(float4*)&k_i[4*j] = *(const float4*)(krow_i + d0 + 4*j);
            }
            #pragma unroll
            for (int r = 0; r < RT; ++r) {
                float q_r[16], q_i[16];
                #pragma unroll
                for (int j = 0; j < 4; ++j) {
                    *(float4*)&q_r[4*j] = *(const float4*)&sQr[r][d0+4*j];
                    *(float4*)&q_i[4*j] = *(const float4*)&sQi[r][d0+4*j];
                }
                #pragma unroll
                for (int dd = 0; dd < 16; ++dd) {
                    zr[r] += q_r[dd]*k_r[dd] + q_i[dd]*k_i[dd];
                    zi[r] += q_i[dd]*k_r[dd] - q_r[dd]*k_i[dd];
                }
            }
        }
        #pragma unroll
        for (int r = 0; r < RT; ++r) { sZr[r][m] = zr[r]*SCALE; sZi[r][m] = zi[r]*SCALE; }
    }
    __syncthreads();
    // phase 2: softmax on magnitude, phase preserved: attn = p * z/|z|
    for (int r = 0; r < RT; ++r) {
        float z0r = sZr[r][tid],     z0i = sZi[r][tid];
        float z1r = sZr[r][tid+256], z1i = sZi[r][tid+256];
        float a0 = sqrtf(z0r*z0r + z0i*z0i);
        float a1 = sqrtf(z1r*z1r + z1i*z1i);
        float mx = blk_max(fmaxf(a0, a1));
        float e0 = expf(a0 - mx), e1 = expf(a1 - mx);
        float inv = 1.f / blk_sum(e0 + e1);
        float p0 = e0*inv, p1 = e1*inv;
        sZr[r][tid]     = a0 > 0.f ? p0*z0r/a0 : p0;
        sZi[r][tid]     = a0 > 0.f ? p0*z0i/a0 : 0.f;
        sZr[r][tid+256] = a1 > 0.f ? p1*z1r/a1 : p1;
        sZi[r][tid+256] = a1 > 0.f ? p1*z1i/a1 : 0.f;
    }
    __syncthreads();
    // phase 3: out[r,d] = sum_m attn[r,m] * v[m,d]
    int d = tid & 63;
    int r0 = tid >> 6;    // handles rows r0 and r0+4
    float o0r=0.f, o0i=0.f, o1r=0.f, o1i=0.f;
    for (int m = 0; m < SEQ; m += 4) {
        float a0r[4], a0i[4], a1r[4], a1i[4];
        *(float4*)a0r = *(const float4*)&sZr[r0][m];
        *(float4*)a0i = *(const float4*)&sZi[r0][m];
        *(float4*)a1r = *(const float4*)&sZr[r0+4][m];
        *(float4*)a1i = *(const float4*)&sZi[r0+4][m];
        #pragma unroll
        for (int j = 0; j < 4; ++j) {
            float vvr = kr[(size_t)(m+j)*DH + d];
            float vvi = ki[(size_t)(m+j)*DH + d];
            o0r += a0r[j]*vvr - a0i[j]*vvi;
            o0i += a0r[j]*vvi + a0i[j]*vvr;
            o1r += a1r[j]*vvr - a1i[j]*vvi;
            o1i += a1r[j]*vvi + a1i[j]*vvr;
        }
    }
    int b = bh >> 3, h = bh & 7;
    size_t off0 = ((size_t)(b*SEQ) + n0 + r0)*DIM + h*DH + d;
    size_t off1 = off0 + (size_t)4*DIM;
    aor[off0] = o0r; aoi[off0] = o0i;
    aor[off1] = o1r; aoi[off1] = o1i;
}

// ---------------- launch ----------------
extern "C" void kernel_launch(void* const* d_in, const int* in_sizes, int n_in,
                              void* d_out, int out_size, void* d_ws, size_t ws_size,
                              hipStream_t stream)
{
    const float* x_real  = (const float*)d_in[0];
    const float* x_imag  = (const float*)d_in[1];
    const float* ln1_g_r = (const float*)d_in[2];
    const float* ln1_b_r = (const float*)d_in[3];
    const float* ln1_g_i = (const float*)d_in[4];
    const float* ln1_b_i = (const float*)d_in[5];
    const float* ln2_g_r = (const float*)d_in[6];
    const float* ln2_b_r = (const float*)d_in[7];
    const float* ln2_g_i = (const float*)d_in[8];
    const float* ln2_b_i = (const float*)d_in[9];
    const float* qkv_w_r = (const float*)d_in[10];
    const float* qkv_w_i = (const float*)d_in[11];
    const float* out_w_r = (const float*)d_in[12];
    const float* out_w_i = (const float*)d_in[13];
    const float* out_b_r = (const float*)d_in[14];
    const float* out_b_i = (const float*)d_in[15];
    const float* ff_w_r  = (const float*)d_in[16];
    const float* ff_w_i  = (const float*)d_in[17];
    const float* stepp   = (const float*)d_in[18];
    const float* lamb    = (const float*)d_in[19];

    const size_t SZ = (size_t)ROWS * DIM;
    float* ws  = (float*)d_ws;
    float* xr  = ws;          float* xi  = ws + SZ;
    float* xnr = ws + 2*SZ;   float* xni = ws + 3*SZ;
    float* whr = ws + 4*SZ;   float* whi = ws + 5*SZ;
    float* aor = xnr;         float* aoi = xni;     // reuse: xn dead after QKV

    hipMemcpyAsync(xr, x_real, SZ*sizeof(float), hipMemcpyDeviceToDevice, stream);
    hipMemcpyAsync(xi, x_imag, SZ*sizeof(float), hipMemcpyDeviceToDevice, stream);

    for (int l = 0; l < DEPTHL; ++l) {
        const size_t WO = (size_t)l*DIM*DIM;
        ln_kernel<<<ROWS, 256, 0, stream>>>(xr, xi,
            ln1_g_r + l*DIM, ln1_b_r + l*DIM, ln1_g_i + l*DIM, ln1_b_i + l*DIM, xnr, xni);
        cgemm<0><<<dim3(32,8), 256, 0, stream>>>(xnr, xni, qkv_w_r + WO, qkv_w_i + WO,
            whr, whi, nullptr, nullptr, nullptr, nullptr, nullptr, nullptr, l);
        attn_kernel<<<dim3(32,64), 256, 0, stream>>>(whr, whi, aor, aoi);
        cgemm<1><<<dim3(32,8), 256, 0, stream>>>(aor, aoi, out_w_r + WO, out_w_i + WO,
            xr, xi, out_b_r + l*DIM, out_b_i + l*DIM, xr, xi, nullptr, nullptr, l);
        ln_kernel<<<ROWS, 256, 0, stream>>>(xr, xi,
            ln2_g_r + l*DIM, ln2_b_r + l*DIM, ln2_g_i + l*DIM, ln2_b_i + l*DIM, xnr, xni);
        cgemm<2><<<dim3(32,8), 256, 0, stream>>>(xnr, xni, ff_w_r + WO, ff_w_i + WO,
            xr, xi, nullptr, nullptr, nullptr, nullptr, stepp, lamb, l);
    }
    hipMemcpyAsync(d_out, xr, SZ*sizeof(float), hipMemcpyDeviceToDevice, stream);
    hipMemcpyAsync((float*)d_out + SZ, xi, SZ*sizeof(float), hipMemcpyDeviceToDevice, stream);
}

// Round 2
// 1677.819 us; speedup vs baseline: 6.9217x; 6.9217x over previous
//
#include <hip/hip_runtime.h>
#include <math.h>

#define DEPTHL 4
#define HEADS 8
#define DH 64
#define DIM 512
#define BATCH 4
#define SEQ 512
#define ROWS (BATCH*SEQ)
#define SCALE 0.125f
#define LNEPS 1e-5f

// ---------------- block reduction helpers ----------------
__device__ __forceinline__ void blk_sum4(float& a, float& b, float& c, float& d) {
    __shared__ float s[16];
    #pragma unroll
    for (int o = 32; o; o >>= 1) {
        a += __shfl_xor(a, o); b += __shfl_xor(b, o);
        c += __shfl_xor(c, o); d += __shfl_xor(d, o);
    }
    int w = threadIdx.x >> 6;
    if ((threadIdx.x & 63) == 0) { s[w*4+0]=a; s[w*4+1]=b; s[w*4+2]=c; s[w*4+3]=d; }
    __syncthreads();
    a = s[0]+s[4]+s[8]+s[12];
    b = s[1]+s[5]+s[9]+s[13];
    c = s[2]+s[6]+s[10]+s[14];
    d = s[3]+s[7]+s[11]+s[15];
    __syncthreads();
}

// ---------------- complex LayerNorm (separate real/imag LN) ----------------
__global__ __launch_bounds__(256) void ln_kernel(
    const float* __restrict__ xr, const float* __restrict__ xi,
    const float* __restrict__ gr, const float* __restrict__ br,
    const float* __restrict__ gi, const float* __restrict__ bi,
    float* __restrict__ outr, float* __restrict__ outi)
{
    int row = blockIdx.x, t = threadIdx.x;
    float2 vr = ((const float2*)(xr + (size_t)row*DIM))[t];
    float2 vi = ((const float2*)(xi + (size_t)row*DIM))[t];
    float sr = vr.x+vr.y, qr = vr.x*vr.x+vr.y*vr.y;
    float si = vi.x+vi.y, qi = vi.x*vi.x+vi.y*vi.y;
    blk_sum4(sr, qr, si, qi);
    float mr = sr*(1.f/DIM), mi_ = si*(1.f/DIM);
    float rr = 1.f/sqrtf(qr*(1.f/DIM)-mr*mr+LNEPS);
    float ri = 1.f/sqrtf(qi*(1.f/DIM)-mi_*mi_+LNEPS);
    float2 g2r = ((const float2*)gr)[t], b2r = ((const float2*)br)[t];
    float2 g2i = ((const float2*)gi)[t], b2i = ((const float2*)bi)[t];
    float2 o_r, o_i;
    o_r.x = (vr.x-mr)*rr*g2r.x + b2r.x;
    o_r.y = (vr.y-mr)*rr*g2r.y + b2r.y;
    o_i.x = (vi.x-mi_)*ri*g2i.x + b2i.x;
    o_i.y = (vi.y-mi_)*ri*g2i.y + b2i.y;
    ((float2*)(outr + (size_t)row*DIM))[t] = o_r;
    ((float2*)(outi + (size_t)row*DIM))[t] = o_i;
}

// ---------------- complex GEMM: out[r,e] = sum_k A[r,k] * W[e,k] ----------------
#define BM 64
#define BN 64
#define BK 16

template<int MODE>
__global__ __launch_bounds__(256) void cgemm(
    const float* __restrict__ Ar, const float* __restrict__ Ai,
    const float* __restrict__ Wr, const float* __restrict__ Wi,
    float* __restrict__ Or, float* __restrict__ Oi,
    const float* __restrict__ biasR, const float* __restrict__ biasI,
    const float* __restrict__ resR, const float* __restrict__ resI,
    const float* __restrict__ stepp, const float* __restrict__ lamb, int layer)
{
    __shared__ float sAr[BK][BM+4], sAi[BK][BM+4], sBr[BK][BN+4], sBi[BK][BN+4];
    int tid = threadIdx.x;
    int bm = blockIdx.x, bn = blockIdx.y;
    int tx = tid & 15, ty = tid >> 4;
    int lrow = tid >> 2, lk = (tid & 3) * 4;
    const float* pAr = Ar + (size_t)(bm*BM + lrow)*DIM + lk;
    const float* pAi = Ai + (size_t)(bm*BM + lrow)*DIM + lk;
    const float* pWr = Wr + (size_t)(bn*BN + lrow)*DIM + lk;
    const float* pWi = Wi + (size_t)(bn*BN + lrow)*DIM + lk;
    float cr[4][4] = {{0.f}}, ci[4][4] = {{0.f}};
    for (int k0 = 0; k0 < DIM; k0 += BK) {
        float a_r[4], a_i[4], w_r[4], w_i[4];
        *(float4*)a_r = *(const float4*)(pAr + k0);
        *(float4*)a_i = *(const float4*)(pAi + k0);
        *(float4*)w_r = *(const float4*)(pWr + k0);
        *(float4*)w_i = *(const float4*)(pWi + k0);
        __syncthreads();
        #pragma unroll
        for (int j = 0; j < 4; ++j) {
            sAr[lk+j][lrow] = a_r[j];
            sAi[lk+j][lrow] = a_i[j];
            sBr[lk+j][lrow] = w_r[j];
            sBi[lk+j][lrow] = w_i[j];
        }
        __syncthreads();
        #pragma unroll
        for (int kk = 0; kk < BK; ++kk) {
            float ar[4], ai[4], br[4], bi[4];
            *(float4*)ar = *(const float4*)&sAr[kk][ty*4];
            *(float4*)ai = *(const float4*)&sAi[kk][ty*4];
            *(float4*)br = *(const float4*)&sBr[kk][tx*4];
            *(float4*)bi = *(const float4*)&sBi[kk][tx*4];
            #pragma unroll
            for (int m = 0; m < 4; ++m)
                #pragma unroll
                for (int n = 0; n < 4; ++n) {
                    cr[m][n] = fmaf(ar[m], br[n], cr[m][n]);
                    cr[m][n] = fmaf(-ai[m], bi[n], cr[m][n]);
                    ci[m][n] = fmaf(ar[m], bi[n], ci[m][n]);
                    ci[m][n] = fmaf(ai[m], br[n], ci[m][n]);
                }
        }
    }
    if (MODE == 0) {
        #pragma unroll
        for (int m = 0; m < 4; ++m) {
            int r = bm*BM + ty*4 + m;
            int b = r >> 9, n = r & (SEQ-1);
            size_t off = ((size_t)(b*HEADS + bn)*SEQ + n)*DH + tx*4;
            *(float4*)(Or + off) = make_float4(cr[m][0], cr[m][1], cr[m][2], cr[m][3]);
            *(float4*)(Oi + off) = make_float4(ci[m][0], ci[m][1], ci[m][2], ci[m][3]);
        }
    } else if (MODE == 1) {
        int e = bn*BN + tx*4;
        float4 bR = *(const float4*)(biasR + e);
        float4 bI = *(const float4*)(biasI + e);
        #pragma unroll
        for (int m = 0; m < 4; ++m) {
            int r = bm*BM + ty*4 + m;
            size_t off = (size_t)r*DIM + e;
            float4 xR = *(const float4*)(resR + off);
            float4 xI = *(const float4*)(resI + off);
            float4 oR, oI;
            oR.x = cr[m][0] + bR.x + xR.x; oR.y = cr[m][1] + bR.y + xR.y;
            oR.z = cr[m][2] + bR.z + xR.z; oR.w = cr[m][3] + bR.w + xR.w;
            oI.x = ci[m][0] + bI.x + xI.x; oI.y = ci[m][1] + bI.y + xI.y;
            oI.z = ci[m][2] + bI.z + xI.z; oI.w = ci[m][3] + bI.w + xI.w;
            *(float4*)(Or + off) = oR;
            *(float4*)(Oi + off) = oI;
        }
    } else {
        float ss = log1pf(expf(stepp[layer]));
        float sl = ss * log1pf(expf(lamb[layer]));
        int e = bn*BN + tx*4;
        #pragma unroll
        for (int m = 0; m < 4; ++m) {
            int r = bm*BM + ty*4 + m;
            size_t off = (size_t)r*DIM + e;
            float4 xR = *(const float4*)(Ar + off);   // xn (A itself)
            float4 xI = *(const float4*)(Ai + off);
            float4 oR, oI;
            oR.x = fmaxf(xR.x + ss*cr[m][0] - sl, 0.f);
            oR.y = fmaxf(xR.y + ss*cr[m][1] - sl, 0.f);
            oR.z = fmaxf(xR.z + ss*cr[m][2] - sl, 0.f);
            oR.w = fmaxf(xR.w + ss*cr[m][3] - sl, 0.f);
            oI.x = fmaxf(xI.x + ss*ci[m][0], 0.f);
            oI.y = fmaxf(xI.y + ss*ci[m][1], 0.f);
            oI.z = fmaxf(xI.z + ss*ci[m][2], 0.f);
            oI.w = fmaxf(xI.w + ss*ci[m][3], 0.f);
            *(float4*)(Or + off) = oR;
            *(float4*)(Oi + off) = oI;
        }
    }
}

// ---------------- complex attention, softmax on |z| with phase preserved ----------------
// Spill-free rewrite: small register tiles, capped unrolls, wave-parallel softmax.
#define RT 8
__global__ __launch_bounds__(256, 4) void attn_kernel(
    const float* __restrict__ whr, const float* __restrict__ whi,  // [B*H, N, DH]
    float* __restrict__ aor, float* __restrict__ aoi)              // [B*N, DIM]
{
    __shared__ float sQr[RT][DH], sQi[RT][DH];
    __shared__ float sZr[RT][SEQ], sZi[RT][SEQ];
    int tid = threadIdx.x;
    int bh = blockIdx.x, rt = blockIdx.y;
    const float* kr = whr + (size_t)bh*SEQ*DH;
    const float* ki = whi + (size_t)bh*SEQ*DH;
    int n0 = rt*RT;
    ((float2*)&sQr[0][0])[tid] = ((const float2*)(kr + (size_t)n0*DH))[tid];
    ((float2*)&sQi[0][0])[tid] = ((const float2*)(ki + (size_t)n0*DH))[tid];
    __syncthreads();

    // phase 1: dots[r,m] = SCALE * sum_d q[r,d] * conj(k[m,d]); thread owns column m
    #pragma unroll 1
    for (int mi = 0; mi < 2; ++mi) {
        int m = mi*256 + tid;
        const float* krow_r = kr + (size_t)m*DH;
        const float* krow_i = ki + (size_t)m*DH;
        float zr[RT], zi[RT];
        #pragma unroll
        for (int r = 0; r < RT; ++r) { zr[r] = 0.f; zi[r] = 0.f; }
        #pragma unroll 2
        for (int d = 0; d < DH; d += 4) {
            float4 k4r = *(const float4*)(krow_r + d);
            float4 k4i = *(const float4*)(krow_i + d);
            #pragma unroll
            for (int r = 0; r < RT; ++r) {
                float4 q4r = *(const float4*)&sQr[r][d];
                float4 q4i = *(const float4*)&sQi[r][d];
                float ar = zr[r], ai = zi[r];
                ar = fmaf(q4r.x, k4r.x, ar); ar = fmaf(q4i.x, k4i.x, ar);
                ai = fmaf(q4i.x, k4r.x, ai); ai = fmaf(-q4r.x, k4i.x, ai);
                ar = fmaf(q4r.y, k4r.y, ar); ar = fmaf(q4i.y, k4i.y, ar);
                ai = fmaf(q4i.y, k4r.y, ai); ai = fmaf(-q4r.y, k4i.y, ai);
                ar = fmaf(q4r.z, k4r.z, ar); ar = fmaf(q4i.z, k4i.z, ar);
                ai = fmaf(q4i.z, k4r.z, ai); ai = fmaf(-q4r.z, k4i.z, ai);
                ar = fmaf(q4r.w, k4r.w, ar); ar = fmaf(q4i.w, k4i.w, ar);
                ai = fmaf(q4i.w, k4r.w, ai); ai = fmaf(-q4r.w, k4i.w, ai);
                zr[r] = ar; zi[r] = ai;
            }
        }
        #pragma unroll
        for (int r = 0; r < RT; ++r) { sZr[r][m] = zr[r]*SCALE; sZi[r][m] = zi[r]*SCALE; }
    }
    __syncthreads();

    // phase 2: softmax on magnitude, phase preserved. Wave w owns rows 2w, 2w+1.
    {
        int w = tid >> 6, lane = tid & 63;
        #pragma unroll 1
        for (int rr = 0; rr < 2; ++rr) {
            int r = w*2 + rr;
            float av[8], ev[8];
            float mx = -1e30f;
            #pragma unroll
            for (int j = 0; j < 8; ++j) {
                int idx = lane + 64*j;
                float zr_ = sZr[r][idx], zi_ = sZi[r][idx];
                av[j] = sqrtf(zr_*zr_ + zi_*zi_);
                mx = fmaxf(mx, av[j]);
            }
            #pragma unroll
            for (int o = 32; o; o >>= 1) mx = fmaxf(mx, __shfl_xor(mx, o));
            float s = 0.f;
            #pragma unroll
            for (int j = 0; j < 8; ++j) { ev[j] = expf(av[j] - mx); s += ev[j]; }
            #pragma unroll
            for (int o = 32; o; o >>= 1) s += __shfl_xor(s, o);
            float inv = 1.f / s;
            #pragma unroll
            for (int j = 0; j < 8; ++j) {
                int idx = lane + 64*j;
                float zr_ = sZr[r][idx], zi_ = sZi[r][idx];
                float p = ev[j] * inv;
                float f = av[j] > 0.f ? p / av[j] : 0.f;
                sZr[r][idx] = av[j] > 0.f ? f*zr_ : p;
                sZi[r][idx] = f*zi_;
            }
        }
    }
    __syncthreads();

    // phase 3: out[r,d] = sum_m attn[r,m] * v[m,d]; thread owns (d, rows r0 & r0+4)
    int d = tid & 63;
    int r0 = tid >> 6;
    float o0r=0.f, o0i=0.f, o1r=0.f, o1i=0.f;
    #pragma unroll 2
    for (int m = 0; m < SEQ; m += 4) {
        float4 a0r = *(const float4*)&sZr[r0][m];
        float4 a0i = *(const float4*)&sZi[r0][m];
        float4 a1r = *(const float4*)&sZr[r0+4][m];
        float4 a1i = *(const float4*)&sZi[r0+4][m];
        #pragma unroll
        for (int j = 0; j < 4; ++j) {
            float vvr = kr[(size_t)(m+j)*DH + d];
            float vvi = ki[(size_t)(m+j)*DH + d];
            float awr = j==0?a0r.x : j==1?a0r.y : j==2?a0r.z : a0r.w;
            float awi = j==0?a0i.x : j==1?a0i.y : j==2?a0i.z : a0i.w;
            float bwr = j==0?a1r.x : j==1?a1r.y : j==2?a1r.z : a1r.w;
            float bwi = j==0?a1i.x : j==1?a1i.y : j==2?a1i.z : a1i.w;
            o0r = fmaf(awr, vvr, o0r); o0r = fmaf(-awi, vvi, o0r);
            o0i = fmaf(awr, vvi, o0i); o0i = fmaf(awi, vvr, o0i);
            o1r = fmaf(bwr, vvr, o1r); o1r = fmaf(-bwi, vvi, o1r);
            o1i = fmaf(bwr, vvi, o1i); o1i = fmaf(bwi, vvr, o1i);
        }
    }
    int b = bh >> 3, h = bh & 7;
    size_t off0 = ((size_t)(b*SEQ) + n0 + r0)*DIM + h*DH + d;
    size_t off1 = off0 + (size_t)4*DIM;
    aor[off0] = o0r; aoi[off0] = o0i;
    aor[off1] = o1r; aoi[off1] = o1i;
}

// ---------------- launch ----------------
extern "C" void kernel_launch(void* const* d_in, const int* in_sizes, int n_in,
                              void* d_out, int out_size, void* d_ws, size_t ws_size,
                              hipStream_t stream)
{
    const float* x_real  = (const float*)d_in[0];
    const float* x_imag  = (const float*)d_in[1];
    const float* ln1_g_r = (const float*)d_in[2];
    const float* ln1_b_r = (const float*)d_in[3];
    const float* ln1_g_i = (const float*)d_in[4];
    const float* ln1_b_i = (const float*)d_in[5];
    const float* ln2_g_r = (const float*)d_in[6];
    const float* ln2_b_r = (const float*)d_in[7];
    const float* ln2_g_i = (const float*)d_in[8];
    const float* ln2_b_i = (const float*)d_in[9];
    const float* qkv_w_r = (const float*)d_in[10];
    const float* qkv_w_i = (const float*)d_in[11];
    const float* out_w_r = (const float*)d_in[12];
    const float* out_w_i = (const float*)d_in[13];
    const float* out_b_r = (const float*)d_in[14];
    const float* out_b_i = (const float*)d_in[15];
    const float* ff_w_r  = (const float*)d_in[16];
    const float* ff_w_i  = (const float*)d_in[17];
    const float* stepp   = (const float*)d_in[18];
    const float* lamb    = (const float*)d_in[19];

    const size_t SZ = (size_t)ROWS * DIM;
    float* ws  = (float*)d_ws;
    float* xr  = ws;          float* xi  = ws + SZ;
    float* xnr = ws + 2*SZ;   float* xni = ws + 3*SZ;
    float* whr = ws + 4*SZ;   float* whi = ws + 5*SZ;
    float* aor = xnr;         float* aoi = xni;     // reuse: xn dead after QKV

    hipMemcpyAsync(xr, x_real, SZ*sizeof(float), hipMemcpyDeviceToDevice, stream);
    hipMemcpyAsync(xi, x_imag, SZ*sizeof(float), hipMemcpyDeviceToDevice, stream);

    for (int l = 0; l < DEPTHL; ++l) {
        const size_t WO = (size_t)l*DIM*DIM;
        ln_kernel<<<ROWS, 256, 0, stream>>>(xr, xi,
            ln1_g_r + l*DIM, ln1_b_r + l*DIM, ln1_g_i + l*DIM, ln1_b_i + l*DIM, xnr, xni);
        cgemm<0><<<dim3(32,8), 256, 0, stream>>>(xnr, xni, qkv_w_r + WO, qkv_w_i + WO,
            whr, whi, nullptr, nullptr, nullptr, nullptr, nullptr, nullptr, l);
        attn_kernel<<<dim3(32,64), 256, 0, stream>>>(whr, whi, aor, aoi);
        cgemm<1><<<dim3(32,8), 256, 0, stream>>>(aor, aoi, out_w_r + WO, out_w_i + WO,
            xr, xi, out_b_r + l*DIM, out_b_i + l*DIM, xr, xi, nullptr, nullptr, l);
        ln_kernel<<<ROWS, 256, 0, stream>>>(xr, xi,
            ln2_g_r + l*DIM, ln2_b_r + l*DIM, ln2_g_i + l*DIM, ln2_b_i + l*DIM, xnr, xni);
        cgemm<2><<<dim3(32,8), 256, 0, stream>>>(xnr, xni, ff_w_r + WO, ff_w_i + WO,
            xr, xi, nullptr, nullptr, nullptr, nullptr, stepp, lamb, l);
    }
    hipMemcpyAsync(d_out, xr, SZ*sizeof(float), hipMemcpyDeviceToDevice, stream);
    hipMemcpyAsync((float*)d_out + SZ, xi, SZ*sizeof(float), hipMemcpyDeviceToDevice, stream);
}

// Round 4
// 610.029 us; speedup vs baseline: 19.0375x; 2.7504x over previous
//
#include <hip/hip_runtime.h>
#include <math.h>

#define DEPTHL 4
#define HEADS 8
#define DH 64
#define DIM 512
#define BATCH 4
#define SEQ 512
#define ROWS (BATCH*SEQ)
#define SCALE 0.125f
#define LNEPS 1e-5f

typedef __attribute__((ext_vector_type(8))) short bfrag;   // 8 bf16 (4 VGPR)
typedef __attribute__((ext_vector_type(4))) float ffrag;   // 4 f32 acc
#define MFMA(a,b,c) __builtin_amdgcn_mfma_f32_16x16x32_bf16(a, b, c, 0, 0, 0)

__device__ __forceinline__ unsigned short f2bf(float f) {
    unsigned int u = __float_as_uint(f);
    u += 0x7fffu + ((u >> 16) & 1u);          // round-to-nearest-even
    return (unsigned short)(u >> 16);
}
__device__ __forceinline__ float bf2f(unsigned short b) {
    return __uint_as_float(((unsigned int)b) << 16);
}

// ---------------- weight fp32 -> bf16 (one layer: 6 x DIM*DIM) ----------------
__global__ __launch_bounds__(256) void convw(
    const float* __restrict__ s0, const float* __restrict__ s1,
    const float* __restrict__ s2, const float* __restrict__ s3,
    const float* __restrict__ s4, const float* __restrict__ s5,
    unsigned short* __restrict__ dst)
{
    int gid = blockIdx.x * 256 + threadIdx.x;
    int idx = gid * 4;
    int seg = idx >> 18;                 // DIM*DIM = 262144 per segment
    int off = idx & 262143;
    const float* s = seg == 0 ? s0 : seg == 1 ? s1 : seg == 2 ? s2 :
                     seg == 3 ? s3 : seg == 4 ? s4 : s5;
    float4 v = *(const float4*)(s + off);
    unsigned long long p = (unsigned long long)f2bf(v.x)
        | ((unsigned long long)f2bf(v.y) << 16)
        | ((unsigned long long)f2bf(v.z) << 32)
        | ((unsigned long long)f2bf(v.w) << 48);
    *(unsigned long long*)(dst + idx) = p;
}

// ---------------- block reduction helper ----------------
__device__ __forceinline__ void blk_sum4(float& a, float& b, float& c, float& d) {
    __shared__ float s[16];
    #pragma unroll
    for (int o = 32; o; o >>= 1) {
        a += __shfl_xor(a, o); b += __shfl_xor(b, o);
        c += __shfl_xor(c, o); d += __shfl_xor(d, o);
    }
    int w = threadIdx.x >> 6;
    if ((threadIdx.x & 63) == 0) { s[w*4+0]=a; s[w*4+1]=b; s[w*4+2]=c; s[w*4+3]=d; }
    __syncthreads();
    a = s[0]+s[4]+s[8]+s[12];
    b = s[1]+s[5]+s[9]+s[13];
    c = s[2]+s[6]+s[10]+s[14];
    d = s[3]+s[7]+s[11]+s[15];
    __syncthreads();
}

// ---------------- complex LayerNorm (fp32 in, bf16 out) ----------------
__global__ __launch_bounds__(256) void ln_kernel(
    const float* __restrict__ xr, const float* __restrict__ xi,
    const float* __restrict__ gr, const float* __restrict__ br,
    const float* __restrict__ gi, const float* __restrict__ bi,
    unsigned short* __restrict__ outr, unsigned short* __restrict__ outi)
{
    int row = blockIdx.x, t = threadIdx.x;
    float2 vr = ((const float2*)(xr + (size_t)row*DIM))[t];
    float2 vi = ((const float2*)(xi + (size_t)row*DIM))[t];
    float sr = vr.x+vr.y, qr = vr.x*vr.x+vr.y*vr.y;
    float si = vi.x+vi.y, qi = vi.x*vi.x+vi.y*vi.y;
    blk_sum4(sr, qr, si, qi);
    float mr = sr*(1.f/DIM), mi_ = si*(1.f/DIM);
    float rr = 1.f/sqrtf(qr*(1.f/DIM)-mr*mr+LNEPS);
    float ri = 1.f/sqrtf(qi*(1.f/DIM)-mi_*mi_+LNEPS);
    float2 g2r = ((const float2*)gr)[t], b2r = ((const float2*)br)[t];
    float2 g2i = ((const float2*)gi)[t], b2i = ((const float2*)bi)[t];
    float o0 = (vr.x-mr)*rr*g2r.x + b2r.x;
    float o1 = (vr.y-mr)*rr*g2r.y + b2r.y;
    float o2 = (vi.x-mi_)*ri*g2i.x + b2i.x;
    float o3 = (vi.y-mi_)*ri*g2i.y + b2i.y;
    unsigned int pr = (unsigned int)f2bf(o0) | ((unsigned int)f2bf(o1) << 16);
    unsigned int pi = (unsigned int)f2bf(o2) | ((unsigned int)f2bf(o3) << 16);
    ((unsigned int*)(outr + (size_t)row*DIM))[t] = pr;
    ((unsigned int*)(outi + (size_t)row*DIM))[t] = pi;
}

// ---------------- bf16 MFMA complex GEMM: out[r,e] = sum_k A[r,k]*W[e,k] ----------------
// Block 256 thr = 4 waves (2x2), 64x64 out tile, direct-from-L2 fragment loads.
// MODE 0: bf16 out in head layout [b,h,n,d] (QKV)
// MODE 1: fp32 out = acc + bias + residual, in-place on x (Wout)
// MODE 2: fp32 out = crelu(xn + ss*acc - ss*lm), xn == A bf16 (FF)
template<int MODE>
__global__ __launch_bounds__(256) void cgemm_mfma(
    const unsigned short* __restrict__ Ar, const unsigned short* __restrict__ Ai,
    const unsigned short* __restrict__ Wr, const unsigned short* __restrict__ Wi,
    unsigned short* __restrict__ Obr, unsigned short* __restrict__ Obi,
    float* __restrict__ Ofr, float* __restrict__ Ofi,
    const float* __restrict__ biasR, const float* __restrict__ biasI,
    const float* __restrict__ stepp, const float* __restrict__ lamb, int layer)
{
    int tid = threadIdx.x;
    int lane = tid & 63;
    int w = tid >> 6, wr = w >> 1, wc = w & 1;
    int lrow = lane & 15, lg = lane >> 4;
    int bm = blockIdx.x, bn = blockIdx.y;

    const unsigned short* pA_r[2]; const unsigned short* pA_i[2];
    const unsigned short* pB_r[2]; const unsigned short* pB_i[2];
    #pragma unroll
    for (int t = 0; t < 2; ++t) {
        int arow = bm*64 + wr*32 + t*16 + lrow;
        int brow = bn*64 + wc*32 + t*16 + lrow;
        pA_r[t] = Ar + (size_t)arow*DIM + lg*8;
        pA_i[t] = Ai + (size_t)arow*DIM + lg*8;
        pB_r[t] = Wr + (size_t)brow*DIM + lg*8;
        pB_i[t] = Wi + (size_t)brow*DIM + lg*8;
    }
    ffrag acc1[2][2], acc2[2][2], acci[2][2];
    #pragma unroll
    for (int a = 0; a < 2; ++a)
    #pragma unroll
    for (int b = 0; b < 2; ++b) {
        acc1[a][b] = (ffrag){0.f,0.f,0.f,0.f};
        acc2[a][b] = (ffrag){0.f,0.f,0.f,0.f};
        acci[a][b] = (ffrag){0.f,0.f,0.f,0.f};
    }

    #pragma unroll 2
    for (int k0 = 0; k0 < DIM; k0 += 32) {
        bfrag a_r[2], a_i[2], b_r[2], b_i[2];
        #pragma unroll
        for (int t = 0; t < 2; ++t) {
            a_r[t] = *(const bfrag*)(pA_r[t] + k0);
            a_i[t] = *(const bfrag*)(pA_i[t] + k0);
            b_r[t] = *(const bfrag*)(pB_r[t] + k0);
            b_i[t] = *(const bfrag*)(pB_i[t] + k0);
        }
        #pragma unroll
        for (int mt = 0; mt < 2; ++mt)
        #pragma unroll
        for (int nt = 0; nt < 2; ++nt) {
            acc1[mt][nt] = MFMA(a_r[mt], b_r[nt], acc1[mt][nt]);
            acc2[mt][nt] = MFMA(a_i[mt], b_i[nt], acc2[mt][nt]);
            acci[mt][nt] = MFMA(a_r[mt], b_i[nt], acci[mt][nt]);
            acci[mt][nt] = MFMA(a_i[mt], b_r[nt], acci[mt][nt]);
        }
    }

    float ss = 0.f, sl = 0.f;
    if (MODE == 2) { ss = log1pf(expf(stepp[layer])); sl = ss * log1pf(expf(lamb[layer])); }

    #pragma unroll
    for (int mt = 0; mt < 2; ++mt)
    #pragma unroll
    for (int nt = 0; nt < 2; ++nt) {
        int E = bn*64 + wc*32 + nt*16 + lrow;
        #pragma unroll
        for (int r = 0; r < 4; ++r) {
            int R = bm*64 + wr*32 + mt*16 + lg*4 + r;
            float re = acc1[mt][nt][r] - acc2[mt][nt][r];
            float im = acci[mt][nt][r];
            if (MODE == 0) {
                int b = R >> 9, n = R & (SEQ-1);
                int h = E >> 6, d = E & 63;
                size_t off = (((size_t)(b*HEADS + h)*SEQ + n) << 6) + d;
                Obr[off] = f2bf(re);
                Obi[off] = f2bf(im);
            } else if (MODE == 1) {
                size_t off = (size_t)R*DIM + E;
                Ofr[off] = re + biasR[E] + Ofr[off];
                Ofi[off] = im + biasI[E] + Ofi[off];
            } else {
                size_t off = (size_t)R*DIM + E;
                float xnr_ = bf2f(Ar[off]), xni_ = bf2f(Ai[off]);
                Ofr[off] = fmaxf(xnr_ + ss*re - sl, 0.f);
                Ofi[off] = fmaxf(xni_ + ss*im, 0.f);
            }
        }
    }
}

// ---------------- MFMA flash attention, softmax on |z| phase preserved ----------------
// grid (32 bh, 8 qtiles of 64). Block = 4 waves, wave owns 16 q rows.
// z computed transposed (A=K, B=Q) so q = lane&15 -> per-lane flash state.
__global__ __launch_bounds__(256) void attn_mfma(
    const unsigned short* __restrict__ whr, const unsigned short* __restrict__ whi,
    unsigned short* __restrict__ aor, unsigned short* __restrict__ aoi)
{
    __shared__ unsigned short sVr[64][40], sVi[64][40];   // V^T [d][m], padded
    __shared__ unsigned short sPr[4][16][40], sPi[4][16][40]; // per-wave P^T [q][m]
    __shared__ unsigned short sO[64][72];                 // output restage
    int tid = threadIdx.x, lane = tid & 63, w = tid >> 6;
    int lrow = lane & 15, lg = lane >> 4;
    int bh = blockIdx.x, qt = blockIdx.y;
    const unsigned short* baseR = whr + ((size_t)bh << 15);   // *512*64
    const unsigned short* baseI = whi + ((size_t)bh << 15);
    int q0 = qt*64 + w*16;

    bfrag qfr[2], qfi[2];
    #pragma unroll
    for (int ks = 0; ks < 2; ++ks) {
        qfr[ks] = *(const bfrag*)(baseR + ((size_t)(q0 + lrow) << 6) + ks*32 + lg*8);
        qfi[ks] = *(const bfrag*)(baseI + ((size_t)(q0 + lrow) << 6) + ks*32 + lg*8);
    }
    float M = -1e30f, S = 0.f;
    ffrag o1[4], o2[4], o3[4];   // O^T accs: SumVrPr, SumViPi, Sum(VrPi+ViPr)
    #pragma unroll
    for (int dt = 0; dt < 4; ++dt) {
        o1[dt] = (ffrag){0.f,0.f,0.f,0.f};
        o2[dt] = (ffrag){0.f,0.f,0.f,0.f};
        o3[dt] = (ffrag){0.f,0.f,0.f,0.f};
    }
    int sm = tid & 31;            // staging: m row
    int sd = (tid >> 5) * 8;      // staging: d group

    #pragma unroll 1
    for (int m0 = 0; m0 < SEQ; m0 += 32) {
        __syncthreads();   // prev PV reads done before sV overwrite
        {   // stage V^T (transposed, shared)
            bfrag vr = *(const bfrag*)(baseR + ((size_t)(m0 + sm) << 6) + sd);
            bfrag vi = *(const bfrag*)(baseI + ((size_t)(m0 + sm) << 6) + sd);
            #pragma unroll
            for (int j = 0; j < 8; ++j) {
                sVr[sd + j][sm] = (unsigned short)vr[j];
                sVi[sd + j][sm] = (unsigned short)vi[j];
            }
        }
        // z^T[m][q] = sum_d K[m,d]*conj-combine Q[q,d]
        ffrag zr[2], zp[2], zm_[2];
        #pragma unroll
        for (int t = 0; t < 2; ++t) {
            zr[t] = (ffrag){0.f,0.f,0.f,0.f};
            zp[t] = (ffrag){0.f,0.f,0.f,0.f};
            zm_[t] = (ffrag){0.f,0.f,0.f,0.f};
        }
        #pragma unroll
        for (int t = 0; t < 2; ++t)
        #pragma unroll
        for (int ks = 0; ks < 2; ++ks) {
            bfrag kr = *(const bfrag*)(baseR + ((size_t)(m0 + t*16 + lrow) << 6) + ks*32 + lg*8);
            bfrag ki = *(const bfrag*)(baseI + ((size_t)(m0 + t*16 + lrow) << 6) + ks*32 + lg*8);
            zr[t]  = MFMA(kr, qfr[ks], zr[t]);
            zr[t]  = MFMA(ki, qfi[ks], zr[t]);
            zp[t]  = MFMA(kr, qfi[ks], zp[t]);
            zm_[t] = MFMA(ki, qfr[ks], zm_[t]);
        }
        // online softmax on |z|; lane's q = lrow, its 8 m: m0 + t*16 + lg*4 + r
        float av[2][4], rv[2][4], iv[2][4];
        float pmax = -1e30f;
        #pragma unroll
        for (int t = 0; t < 2; ++t)
        #pragma unroll
        for (int r = 0; r < 4; ++r) {
            float zrv = zr[t][r] * SCALE;
            float ziv = (zp[t][r] - zm_[t][r]) * SCALE;
            float a = sqrtf(zrv*zrv + ziv*ziv);
            av[t][r] = a; rv[t][r] = zrv; iv[t][r] = ziv;
            pmax = fmaxf(pmax, a);
        }
        pmax = fmaxf(pmax, __shfl_xor(pmax, 16));
        pmax = fmaxf(pmax, __shfl_xor(pmax, 32));
        float Mnew = fmaxf(M, pmax);
        float f = expf(M - Mnew);
        M = Mnew;
        S *= f;
        #pragma unroll
        for (int dt = 0; dt < 4; ++dt) { o1[dt] *= f; o2[dt] *= f; o3[dt] *= f; }
        float ssum = 0.f;
        #pragma unroll
        for (int t = 0; t < 2; ++t) {
            float ur[4], ui[4];
            #pragma unroll
            for (int r = 0; r < 4; ++r) {
                float a = av[t][r];
                float ee = expf(a - M);
                ssum += ee;
                float inva = a > 0.f ? ee / a : 0.f;
                ur[r] = a > 0.f ? inva * rv[t][r] : ee;
                ui[r] = inva * iv[t][r];
            }
            uint2 wpr, wpi;
            wpr.x = (unsigned int)f2bf(ur[0]) | ((unsigned int)f2bf(ur[1]) << 16);
            wpr.y = (unsigned int)f2bf(ur[2]) | ((unsigned int)f2bf(ur[3]) << 16);
            wpi.x = (unsigned int)f2bf(ui[0]) | ((unsigned int)f2bf(ui[1]) << 16);
            wpi.y = (unsigned int)f2bf(ui[2]) | ((unsigned int)f2bf(ui[3]) << 16);
            *(uint2*)&sPr[w][lrow][t*16 + lg*4] = wpr;
            *(uint2*)&sPi[w][lrow][t*16 + lg*4] = wpi;
        }
        ssum += __shfl_xor(ssum, 16);
        ssum += __shfl_xor(ssum, 32);
        S += ssum;
        __syncthreads();   // sV staged, sP written
        // PV: O^T[d][q] += V^T * P
        bfrag pr = *(const bfrag*)&sPr[w][lrow][lg*8];
        bfrag pi = *(const bfrag*)&sPi[w][lrow][lg*8];
        #pragma unroll
        for (int dt = 0; dt < 4; ++dt) {
            bfrag vr = *(const bfrag*)&sVr[dt*16 + lrow][lg*8];
            bfrag vi = *(const bfrag*)&sVi[dt*16 + lrow][lg*8];
            o1[dt] = MFMA(vr, pr, o1[dt]);
            o2[dt] = MFMA(vi, pi, o2[dt]);
            o3[dt] = MFMA(vr, pi, o3[dt]);
            o3[dt] = MFMA(vi, pr, o3[dt]);
        }
    }

    // epilogue: O = O^T/S, restage via LDS for coalesced bf16 writes
    float invS = 1.f / S;
    int b = bh >> 3, h = bh & 7;
    __syncthreads();
    #pragma unroll
    for (int dt = 0; dt < 4; ++dt) {
        uint2 p;
        p.x = (unsigned int)f2bf((o1[dt][0]-o2[dt][0])*invS)
            | ((unsigned int)f2bf((o1[dt][1]-o2[dt][1])*invS) << 16);
        p.y = (unsigned int)f2bf((o1[dt][2]-o2[dt][2])*invS)
            | ((unsigned int)f2bf((o1[dt][3]-o2[dt][3])*invS) << 16);
        *(uint2*)&sO[w*16 + lrow][dt*16 + lg*4] = p;
    }
    __syncthreads();
    {
        int qrow = tid >> 2, d0 = (tid & 3) * 16;   // 16 elems/thread = 2 bfrags
        bfrag v0 = *(const bfrag*)&sO[qrow][d0];
        bfrag v1 = *(const bfrag*)&sO[qrow][d0 + 8];
        size_t off = (((size_t)(b*SEQ + qt*64 + qrow)) << 9) + h*64 + d0;
        *(bfrag*)(aor + off) = v0;
        *(bfrag*)(aor + off + 8) = v1;
    }
    __syncthreads();
    #pragma unroll
    for (int dt = 0; dt < 4; ++dt) {
        uint2 p;
        p.x = (unsigned int)f2bf(o3[dt][0]*invS) | ((unsigned int)f2bf(o3[dt][1]*invS) << 16);
        p.y = (unsigned int)f2bf(o3[dt][2]*invS) | ((unsigned int)f2bf(o3[dt][3]*invS) << 16);
        *(uint2*)&sO[w*16 + lrow][dt*16 + lg*4] = p;
    }
    __syncthreads();
    {
        int qrow = tid >> 2, d0 = (tid & 3) * 16;
        bfrag v0 = *(const bfrag*)&sO[qrow][d0];
        bfrag v1 = *(const bfrag*)&sO[qrow][d0 + 8];
        size_t off = (((size_t)(b*SEQ + qt*64 + qrow)) << 9) + h*64 + d0;
        *(bfrag*)(aoi + off) = v0;
        *(bfrag*)(aoi + off + 8) = v1;
    }
}

// ---------------- launch ----------------
extern "C" void kernel_launch(void* const* d_in, const int* in_sizes, int n_in,
                              void* d_out, int out_size, void* d_ws, size_t ws_size,
                              hipStream_t stream)
{
    const float* x_real  = (const float*)d_in[0];
    const float* x_imag  = (const float*)d_in[1];
    const float* ln1_g_r = (const float*)d_in[2];
    const float* ln1_b_r = (const float*)d_in[3];
    const float* ln1_g_i = (const float*)d_in[4];
    const float* ln1_b_i = (const float*)d_in[5];
    const float* ln2_g_r = (const float*)d_in[6];
    const float* ln2_b_r = (const float*)d_in[7];
    const float* ln2_g_i = (const float*)d_in[8];
    const float* ln2_b_i = (const float*)d_in[9];
    const float* qkv_w_r = (const float*)d_in[10];
    const float* qkv_w_i = (const float*)d_in[11];
    const float* out_w_r = (const float*)d_in[12];
    const float* out_w_i = (const float*)d_in[13];
    const float* out_b_r = (const float*)d_in[14];
    const float* out_b_i = (const float*)d_in[15];
    const float* ff_w_r  = (const float*)d_in[16];
    const float* ff_w_i  = (const float*)d_in[17];
    const float* stepp   = (const float*)d_in[18];
    const float* lamb    = (const float*)d_in[19];

    const size_t SZ = (size_t)ROWS * DIM;       // 1M elems
    const size_t WSEG = (size_t)DIM * DIM;      // 256K elems
    float* xr = (float*)d_ws;
    float* xi = xr + SZ;
    unsigned short* xnr = (unsigned short*)(xi + SZ);
    unsigned short* xni = xnr + SZ;
    unsigned short* whr = xni + SZ;
    unsigned short* whi = whr + SZ;
    unsigned short* aor = whi + SZ;
    unsigned short* aoi = aor + SZ;
    unsigned short* wb  = aoi + SZ;             // 6*WSEG bf16 (one layer)

    hipMemcpyAsync(xr, x_real, SZ*sizeof(float), hipMemcpyDeviceToDevice, stream);
    hipMemcpyAsync(xi, x_imag, SZ*sizeof(float), hipMemcpyDeviceToDevice, stream);

    for (int l = 0; l < DEPTHL; ++l) {
        const size_t WO = (size_t)l * WSEG;
        convw<<<1536, 256, 0, stream>>>(qkv_w_r + WO, qkv_w_i + WO, out_w_r + WO,
                                        out_w_i + WO, ff_w_r + WO, ff_w_i + WO, wb);
        ln_kernel<<<ROWS, 256, 0, stream>>>(xr, xi,
            ln1_g_r + l*DIM, ln1_b_r + l*DIM, ln1_g_i + l*DIM, ln1_b_i + l*DIM, xnr, xni);
        cgemm_mfma<0><<<dim3(32, 8), 256, 0, stream>>>(xnr, xni, wb, wb + WSEG,
            whr, whi, nullptr, nullptr, nullptr, nullptr, nullptr, nullptr, l);
        attn_mfma<<<dim3(32, 8), 256, 0, stream>>>(whr, whi, aor, aoi);
        cgemm_mfma<1><<<dim3(32, 8), 256, 0, stream>>>(aor, aoi, wb + 2*WSEG, wb + 3*WSEG,
            nullptr, nullptr, xr, xi, out_b_r + l*DIM, out_b_i + l*DIM, nullptr, nullptr, l);
        ln_kernel<<<ROWS, 256, 0, stream>>>(xr, xi,
            ln2_g_r + l*DIM, ln2_b_r + l*DIM, ln2_g_i + l*DIM, ln2_b_i + l*DIM, xnr, xni);
        cgemm_mfma<2><<<dim3(32, 8), 256, 0, stream>>>(xnr, xni, wb + 4*WSEG, wb + 5*WSEG,
            nullptr, nullptr, xr, xi, nullptr, nullptr, stepp, lamb, l);
    }
    hipMemcpyAsync(d_out, xr, SZ*sizeof(float), hipMemcpyDeviceToDevice, stream);
    hipMemcpyAsync((float*)d_out + SZ, xi, SZ*sizeof(float), hipMemcpyDeviceToDevice, stream);
}